// Round 7
// baseline (143.356 us; speedup 1.0000x reference)
//
#include <hip/hip_runtime.h>

// GenomeNet: B=4096, N_IN=W=N_OUT=1024, L=8 hidden, D=16 fan-in.
// R7: batch-contiguous shared rows. LDS act layout = [1024 nodes][8 batches]
// fp16 (16 B rows). Lane = (node-slot = tid>>2, batch-pair = tid&3); a gather
// instruction reads 16 ROWS x 16 B = 256 B where the random src index picks
// the row and adjacent lanes span it contiguously -> only 16 random bank
// windows per instr (vs 64 per-lane windows in R3-R6), so E[max bank load]
// imbalance collapses. Per edge: 1 ds_read_b32 (2 batches) + 2 cvt + 2 f32
// fma. Grid 512 x 512 threads, TB=8 batches/block, 2 blocks/CU (2 x 16 KB
// ping-pong LDS each) for overlapped barrier domains. fp32 accumulate,
// fast tanh — numerics identical to R5.

#define TB       8
#define W_NODES  1024
#define LAYERS   8
#define ROW_DW   4                      // dwords per node row: 8 batches fp16
#define BUF_DW   (W_NODES * ROW_DW)     // 4096 dwords = 16 KB

typedef _Float16 h2 __attribute__((ext_vector_type(2)));

__device__ __forceinline__ float fast_tanh(float x) {
    // tanh(x) = 1 - 2/(e^{2x}+1)
    float a = __builtin_amdgcn_exp2f(x * 2.8853900817779268f);
    return 1.0f - 2.0f * __builtin_amdgcn_rcpf(a + 1.0f);
}

__global__ __launch_bounds__(512, 4) void genome_net(
    const float* __restrict__ x,
    const int*   __restrict__ src_hidden,
    const float* __restrict__ w_hidden,
    const int*   __restrict__ src_out,
    const float* __restrict__ w_out,
    float*       __restrict__ out)
{
    extern __shared__ unsigned int ldsu[];
    unsigned int* bufA = ldsu;            // [1024 rows][4 dwords]
    unsigned int* bufB = ldsu + BUF_DW;

    const int tid  = threadIdx.x;         // 0..511
    const int nrow = tid >> 2;            // node-slot 0..127
    const int bp   = tid & 3;             // batch-pair 0..3 (batches 2bp,2bp+1)
    const int b0   = blockIdx.x * TB;

    // ---- Stage x: thread stages input rows tid and tid+512 (fp32 -> fp16x2).
    #pragma unroll
    for (int r = 0; r < 2; ++r) {
        const int t = tid + (r << 9);
        #pragma unroll
        for (int jp = 0; jp < 4; ++jp) {
            const float a0 = x[(size_t)(b0 + 2 * jp    ) * W_NODES + t];
            const float a1 = x[(size_t)(b0 + 2 * jp + 1) * W_NODES + t];
            h2 h; h[0] = (_Float16)a0; h[1] = (_Float16)a1;
            bufA[(t << 2) + jp] = __builtin_bit_cast(unsigned int, h);
        }
    }
    __syncthreads();

    const unsigned int* rd = bufA;
    unsigned int*       wr = bufB;

    #pragma unroll 1
    for (int l = 0; l < LAYERS; ++l) {
        #pragma unroll 1
        for (int g = 0; g < 8; ++g) {
            const int n    = (g << 7) + nrow;
            const int base = ((l << 10) + n) << 4;
            const int4*   sp = (const int4*)(src_hidden + base);
            const float4* wp = (const float4*)(w_hidden + base);
            int si[16]; float wi[16];
            #pragma unroll
            for (int q = 0; q < 4; ++q) {
                const int4 s4 = sp[q]; const float4 w4 = wp[q];
                si[4*q+0] = s4.x; si[4*q+1] = s4.y; si[4*q+2] = s4.z; si[4*q+3] = s4.w;
                wi[4*q+0] = w4.x; wi[4*q+1] = w4.y; wi[4*q+2] = w4.z; wi[4*q+3] = w4.w;
            }

            float acc0 = 0.0f, acc1 = 0.0f;
            #pragma unroll
            for (int d = 0; d < 16; ++d) {
                const h2 v = __builtin_bit_cast(h2, rd[(si[d] << 2) + bp]);
                acc0 = fmaf((float)v[0], wi[d], acc0);
                acc1 = fmaf((float)v[1], wi[d], acc1);
            }

            h2 o; o[0] = (_Float16)fast_tanh(acc0); o[1] = (_Float16)fast_tanh(acc1);
            // Write: lane-linear addresses -> 256 B contiguous per wave (free).
            wr[(n << 2) + bp] = __builtin_bit_cast(unsigned int, o);
        }
        __syncthreads();
        const unsigned int* tmp = rd; rd = wr; wr = (unsigned int*)tmp;
    }

    // ---- Output layer: identity activation, fp32 accumulate + stores.
    #pragma unroll 1
    for (int g = 0; g < 8; ++g) {
        const int n    = (g << 7) + nrow;
        const int base = n << 4;
        const int4*   sp = (const int4*)(src_out + base);
        const float4* wp = (const float4*)(w_out + base);
        int si[16]; float wi[16];
        #pragma unroll
        for (int q = 0; q < 4; ++q) {
            const int4 s4 = sp[q]; const float4 w4 = wp[q];
            si[4*q+0] = s4.x; si[4*q+1] = s4.y; si[4*q+2] = s4.z; si[4*q+3] = s4.w;
            wi[4*q+0] = w4.x; wi[4*q+1] = w4.y; wi[4*q+2] = w4.z; wi[4*q+3] = w4.w;
        }

        float acc0 = 0.0f, acc1 = 0.0f;
        #pragma unroll
        for (int d = 0; d < 16; ++d) {
            const h2 v = __builtin_bit_cast(h2, rd[(si[d] << 2) + bp]);
            acc0 = fmaf((float)v[0], wi[d], acc0);
            acc1 = fmaf((float)v[1], wi[d], acc1);
        }

        out[(size_t)(b0 + 2 * bp    ) * W_NODES + n] = acc0;
        out[(size_t)(b0 + 2 * bp + 1) * W_NODES + n] = acc1;
    }
}

extern "C" void kernel_launch(void* const* d_in, const int* in_sizes, int n_in,
                              void* d_out, int out_size, void* d_ws, size_t ws_size,
                              hipStream_t stream) {
    const float* x  = (const float*)d_in[0];
    const int*   sh = (const int*)  d_in[1];
    const float* wh = (const float*)d_in[2];
    const int*   so = (const int*)  d_in[3];
    const float* wo = (const float*)d_in[4];
    float* out = (float*)d_out;

    const int shmem = 2 * BUF_DW * (int)sizeof(unsigned int);   // 32768 B
    hipFuncSetAttribute(reinterpret_cast<const void*>(genome_net),
                        hipFuncAttributeMaxDynamicSharedMemorySize, shmem);

    genome_net<<<dim3(4096 / TB), dim3(512), shmem, stream>>>(
        x, sh, wh, so, wo, out);
}

// Round 8
// 131.560 us; speedup vs baseline: 1.0897x; 1.0897x over previous
//
#include <hip/hip_runtime.h>

// GenomeNet: B=4096, N_IN=W=N_OUT=1024, L=8 hidden, D=16 fan-in.
// R8 = R5 main kernel (TB=8, fp16 16B rows, group=s%8, 2 blocks/CU, 4608
// ds_read_b128/CU = instruction floor) + a register-only pre-pass that
// bank-schedules each node's 16 edges: Batcher sort by (s&7) then rotation
// by 2*(node&7), so gather slot d across 64 consecutive lanes hits each of
// the 8 four-bank groups ~8x (balanced). R4's pre-pass failed on scratch
// spills (dynamic local indexing); this one is fully unrolled, registers
// only. R7 lesson: LDS is issue-limited — never widen the instruction count.

#define TB       8
#define W_NODES  1024
#define LAYERS   8
#define ROW_H    8                     // halfs per node row (16 B)
#define BUF_H    (W_NODES * ROW_H)     // 8192 halfs = 16 KB
#define HID_ROWS (LAYERS * W_NODES)    // 8192 hidden rows... (8*1024 = 8192)
#define OUT_ROWS (W_NODES)

typedef _Float16 h8 __attribute__((ext_vector_type(8)));

__device__ __forceinline__ float fast_tanh(float x) {
    // tanh(x) = 1 - 2/(e^{2x}+1)
    float a = __builtin_amdgcn_exp2f(x * 2.8853900817779268f);
    return 1.0f - 2.0f * __builtin_amdgcn_rcpf(a + 1.0f);
}

// ---- Pre-pass: per row, sort 16 (s,w) pairs by key (s&7) with a fully
// unrolled Batcher odd-even mergesort (63 CEs, branchless, registers only),
// then store rotated by 2*(n&7): out[d] = sorted[(d + rot) & 15].
__global__ __launch_bounds__(256) void sched_rows(
    const int*   __restrict__ sh, const float* __restrict__ wh,
    const int*   __restrict__ so, const float* __restrict__ wo,
    int* __restrict__ ps_h, float* __restrict__ pw_h,
    int* __restrict__ ps_o, float* __restrict__ pw_o)
{
    const int rid = blockIdx.x * 256 + threadIdx.x;     // 0..9215
    const bool hid = rid < HID_ROWS;
    const int  r   = hid ? rid : rid - HID_ROWS;        // row within table
    if (!hid && r >= OUT_ROWS) return;
    const int  n    = r & 1023;                          // node within layer
    const int  base = r << 4;

    const int*   srcp = hid ? sh + base : so + base;
    const float* wp   = hid ? wh + base : wo + base;
    int*   pd = (hid ? ps_h : ps_o) + base;
    float* wd = (hid ? pw_h : pw_o) + base;

    int s[16]; float wt[16];
    {
        const int4*   s4 = (const int4*)srcp;
        const float4* w4 = (const float4*)wp;
        #pragma unroll
        for (int q = 0; q < 4; ++q) {
            const int4 a = s4[q]; const float4 b = w4[q];
            s[4*q+0] = a.x; s[4*q+1] = a.y; s[4*q+2] = a.z; s[4*q+3] = a.w;
            wt[4*q+0] = b.x; wt[4*q+1] = b.y; wt[4*q+2] = b.z; wt[4*q+3] = b.w;
        }
    }

    // Batcher odd-even mergesort, N=16; all indices compile-time constants.
    #pragma unroll
    for (int p = 1; p < 16; p <<= 1) {
        #pragma unroll
        for (int k = p; k >= 1; k >>= 1) {
            #pragma unroll
            for (int j = k % p; j + k < 16; j += 2 * k) {
                #pragma unroll
                for (int i = 0; i < k; ++i) {
                    if (i + j + k < 16 &&
                        (i + j) / (2 * p) == (i + j + k) / (2 * p)) {
                        const int a = i + j, b = i + j + k;
                        const bool sw = (s[a] & 7) > (s[b] & 7);
                        const int   s_lo = sw ? s[b]  : s[a];
                        const int   s_hi = sw ? s[a]  : s[b];
                        const float w_lo = sw ? wt[b] : wt[a];
                        const float w_hi = sw ? wt[a] : wt[b];
                        s[a] = s_lo; s[b] = s_hi; wt[a] = w_lo; wt[b] = w_hi;
                    }
                }
            }
        }
    }

    const int rot = (n & 7) << 1;
    #pragma unroll
    for (int i = 0; i < 16; ++i) {       // out[(i - rot) & 15] = sorted[i]
        const int d = (i - rot) & 15;
        pd[d] = s[i];
        wd[d] = wt[i];
    }
}

__global__ __launch_bounds__(1024, 8) void genome_net(
    const float* __restrict__ x,
    const int*   __restrict__ src_hidden,
    const float* __restrict__ w_hidden,
    const int*   __restrict__ src_out,
    const float* __restrict__ w_out,
    float*       __restrict__ out)
{
    extern __shared__ _Float16 lds[];
    _Float16* bufA = lds;              // [1024 nodes][8 batch] fp16, 16 KB
    _Float16* bufB = lds + BUF_H;

    const int t  = threadIdx.x;        // node / output index
    const int b0 = blockIdx.x * TB;    // batch tile base

    // ---- Stage x: fp32 -> fp16 row. Coalesced 4 KB per j across the block.
    {
        h8 hv;
        #pragma unroll
        for (int j = 0; j < TB; ++j)
            hv[j] = (_Float16)x[(size_t)(b0 + j) * W_NODES + t];
        *(h8*)(bufA + t * ROW_H) = hv;
    }
    __syncthreads();

    _Float16* rd = bufA;
    _Float16* wr = bufB;

    #pragma unroll 1
    for (int l = 0; l < LAYERS; ++l) {
        const int row = (l << 10) + t;
        const int4*   sp = (const int4*)(src_hidden) + (row << 2);
        const float4* wp = (const float4*)(w_hidden) + (row << 2);
        int4   s4[4]; float4 w4[4];
        #pragma unroll
        for (int q = 0; q < 4; ++q) { s4[q] = sp[q]; w4[q] = wp[q]; }
        int   si[16]; float wi[16];
        #pragma unroll
        for (int q = 0; q < 4; ++q) {
            si[4*q+0] = s4[q].x; si[4*q+1] = s4[q].y;
            si[4*q+2] = s4[q].z; si[4*q+3] = s4[q].w;
            wi[4*q+0] = w4[q].x; wi[4*q+1] = w4[q].y;
            wi[4*q+2] = w4[q].z; wi[4*q+3] = w4[q].w;
        }

        float acc[TB];
        #pragma unroll
        for (int j = 0; j < TB; ++j) acc[j] = 0.0f;

        #pragma unroll
        for (int d = 0; d < 16; ++d) {
            const h8 v = *(const h8*)(rd + (si[d] << 3));
            const float w = wi[d];
            #pragma unroll
            for (int j = 0; j < TB; ++j)
                acc[j] = fmaf((float)v[j], w, acc[j]);
        }

        h8 hv;
        #pragma unroll
        for (int j = 0; j < TB; ++j) hv[j] = (_Float16)fast_tanh(acc[j]);
        *(h8*)(wr + t * ROW_H) = hv;   // group = t%8: perfectly balanced

        __syncthreads();
        _Float16* tmp = rd; rd = wr; wr = tmp;
    }

    // ---- Output layer: identity activation, fp32 accumulate + stores.
    {
        const int4*   sp = (const int4*)(src_out) + (t << 2);
        const float4* wp = (const float4*)(w_out) + (t << 2);
        int4   s4[4]; float4 w4[4];
        #pragma unroll
        for (int q = 0; q < 4; ++q) { s4[q] = sp[q]; w4[q] = wp[q]; }
        int   si[16]; float wi[16];
        #pragma unroll
        for (int q = 0; q < 4; ++q) {
            si[4*q+0] = s4[q].x; si[4*q+1] = s4[q].y;
            si[4*q+2] = s4[q].z; si[4*q+3] = s4[q].w;
            wi[4*q+0] = w4[q].x; wi[4*q+1] = w4[q].y;
            wi[4*q+2] = w4[q].z; wi[4*q+3] = w4[q].w;
        }

        float acc[TB];
        #pragma unroll
        for (int j = 0; j < TB; ++j) acc[j] = 0.0f;

        #pragma unroll
        for (int d = 0; d < 16; ++d) {
            const h8 v = *(const h8*)(rd + (si[d] << 3));
            const float w = wi[d];
            #pragma unroll
            for (int j = 0; j < TB; ++j)
                acc[j] = fmaf((float)v[j], w, acc[j]);
        }

        // Coalesced 4 KB stores per j across the block.
        #pragma unroll
        for (int j = 0; j < TB; ++j)
            out[(size_t)(b0 + j) * W_NODES + t] = acc[j];
    }
}

extern "C" void kernel_launch(void* const* d_in, const int* in_sizes, int n_in,
                              void* d_out, int out_size, void* d_ws, size_t ws_size,
                              hipStream_t stream) {
    const float* x  = (const float*)d_in[0];
    const int*   sh = (const int*)  d_in[1];
    const float* wh = (const float*)d_in[2];
    const int*   so = (const int*)  d_in[3];
    const float* wo = (const float*)d_in[4];
    float* out = (float*)d_out;

    // d_ws layout: ps_hidden | pw_hidden | ps_out | pw_out
    const size_t HID  = (size_t)HID_ROWS * 16;     // 131072 edges
    const size_t OUTE = (size_t)OUT_ROWS * 16;     // 16384 edges
    const size_t need = (HID + OUTE) * 8;          // ~1.18 MB

    const int*   sh_use = sh; const float* wh_use = wh;
    const int*   so_use = so; const float* wo_use = wo;

    if (ws_size >= need) {
        int*   ps_h = (int*)d_ws;
        float* pw_h = (float*)((char*)d_ws + HID * 4);
        int*   ps_o = (int*)((char*)d_ws + HID * 8);
        float* pw_o = (float*)((char*)d_ws + HID * 8 + OUTE * 4);
        const int nrows = HID_ROWS + OUT_ROWS;     // 9216, boundary wave-aligned
        sched_rows<<<dim3((nrows + 255) / 256), dim3(256), 0, stream>>>(
            sh, wh, so, wo, ps_h, pw_h, ps_o, pw_o);
        sh_use = ps_h; wh_use = pw_h; so_use = ps_o; wo_use = pw_o;
    }

    const int shmem = 2 * BUF_H * (int)sizeof(_Float16);   // 32768 B
    hipFuncSetAttribute(reinterpret_cast<const void*>(genome_net),
                        hipFuncAttributeMaxDynamicSharedMemorySize, shmem);

    genome_net<<<dim3(4096 / TB), dim3(1024), shmem, stream>>>(
        x, sh_use, wh_use, so_use, wo_use, out);
}

// Round 9
// 113.593 us; speedup vs baseline: 1.2620x; 1.1582x over previous
//
#include <hip/hip_runtime.h>

// GenomeNet: B=4096, N_IN=W=N_OUT=1024, L=8 hidden, D=16 fan-in.
// R9 = R5/R6 structure (TB=8, fp16 16B rows, bank-group=s%8, 512 blocks x
// 1024 thr, 2 blocks/CU, 4608 ds_read_b128/CU = instruction floor), with the
// 16 edge-gathers forced into a depth-4 software pipeline using
// __builtin_amdgcn_sched_barrier(0) fences (R6's hand pipeline was sunk back
// to depth-2 by the scheduler: VGPR stayed 32). No pre-pass: R4/R8 showed
// conflict-scheduling recovers less than its launch+kernel cost; conflicts
// (~8 cyc/instr) are inherent to random per-lane 16B windows. R7 showed the
// LDS pipe is issue-limited, so never widen the instruction count.

#define TB       8
#define W_NODES  1024
#define LAYERS   8
#define ROW_H    8                     // halfs per node row (16 B)
#define BUF_H    (W_NODES * ROW_H)     // 8192 halfs = 16 KB

typedef _Float16 h8 __attribute__((ext_vector_type(8)));

#define SB() __builtin_amdgcn_sched_barrier(0)

__device__ __forceinline__ float fast_tanh(float x) {
    // tanh(x) = 1 - 2/(e^{2x}+1)
    float a = __builtin_amdgcn_exp2f(x * 2.8853900817779268f);
    return 1.0f - 2.0f * __builtin_amdgcn_rcpf(a + 1.0f);
}

// 16 edge-gathers, depth-4 rolling pipeline, fences forbid load sinking.
__device__ __forceinline__ void gather16(const _Float16* __restrict__ rd,
                                         const int* __restrict__ si,
                                         const float* __restrict__ wi,
                                         float* __restrict__ acc)
{
#define LDV(i) (*(const h8*)(rd + (si[i] << 3)))
#define FMA8(g, w)                                        \
    do {                                                  \
        const float _w = (w);                             \
        _Pragma("unroll")                                 \
        for (int j = 0; j < TB; ++j)                      \
            acc[j] = fmaf((float)(g)[j], _w, acc[j]);     \
    } while (0)

    h8 p0 = LDV(0); h8 p1 = LDV(1); h8 p2 = LDV(2); h8 p3 = LDV(3);
    SB();
    FMA8(p0, wi[0]);  FMA8(p1, wi[1]);
    SB();
    p0 = LDV(4); p1 = LDV(5);
    SB();
    FMA8(p2, wi[2]);  FMA8(p3, wi[3]);
    SB();
    p2 = LDV(6); p3 = LDV(7);
    SB();
    FMA8(p0, wi[4]);  FMA8(p1, wi[5]);
    SB();
    p0 = LDV(8); p1 = LDV(9);
    SB();
    FMA8(p2, wi[6]);  FMA8(p3, wi[7]);
    SB();
    p2 = LDV(10); p3 = LDV(11);
    SB();
    FMA8(p0, wi[8]);  FMA8(p1, wi[9]);
    SB();
    p0 = LDV(12); p1 = LDV(13);
    SB();
    FMA8(p2, wi[10]); FMA8(p3, wi[11]);
    SB();
    p2 = LDV(14); p3 = LDV(15);
    SB();
    FMA8(p0, wi[12]); FMA8(p1, wi[13]);
    FMA8(p2, wi[14]); FMA8(p3, wi[15]);
#undef LDV
#undef FMA8
}

__global__ __launch_bounds__(1024, 8) void genome_net(
    const float* __restrict__ x,
    const int*   __restrict__ src_hidden,
    const float* __restrict__ w_hidden,
    const int*   __restrict__ src_out,
    const float* __restrict__ w_out,
    float*       __restrict__ out)
{
    extern __shared__ _Float16 lds[];
    _Float16* bufA = lds;              // [1024 nodes][8 batch] fp16, 16 KB
    _Float16* bufB = lds + BUF_H;

    const int t  = threadIdx.x;        // node / output index
    const int b0 = blockIdx.x * TB;    // batch tile base

    // ---- Stage x: fp32 -> fp16 row. Coalesced 4 KB per j across the block.
    {
        h8 hv;
        #pragma unroll
        for (int j = 0; j < TB; ++j)
            hv[j] = (_Float16)x[(size_t)(b0 + j) * W_NODES + t];
        *(h8*)(bufA + t * ROW_H) = hv;
    }
    __syncthreads();

    _Float16* rd = bufA;
    _Float16* wr = bufB;

    #pragma unroll 1
    for (int l = 0; l < LAYERS; ++l) {
        const int row = (l << 10) + t;
        const int4*   sp = (const int4*)(src_hidden) + (row << 2);
        const float4* wp = (const float4*)(w_hidden) + (row << 2);
        int4   s4[4]; float4 w4[4];
        #pragma unroll
        for (int q = 0; q < 4; ++q) { s4[q] = sp[q]; w4[q] = wp[q]; }
        int   si[16]; float wi[16];
        #pragma unroll
        for (int q = 0; q < 4; ++q) {
            si[4*q+0] = s4[q].x; si[4*q+1] = s4[q].y;
            si[4*q+2] = s4[q].z; si[4*q+3] = s4[q].w;
            wi[4*q+0] = w4[q].x; wi[4*q+1] = w4[q].y;
            wi[4*q+2] = w4[q].z; wi[4*q+3] = w4[q].w;
        }

        float acc[TB];
        #pragma unroll
        for (int j = 0; j < TB; ++j) acc[j] = 0.0f;

        gather16(rd, si, wi, acc);

        h8 hv;
        #pragma unroll
        for (int j = 0; j < TB; ++j) hv[j] = (_Float16)fast_tanh(acc[j]);
        *(h8*)(wr + t * ROW_H) = hv;   // group = t%8: perfectly balanced

        __syncthreads();
        _Float16* tmp = rd; rd = wr; wr = tmp;
    }

    // ---- Output layer: identity activation, fp32 accumulate + stores.
    {
        const int4*   sp = (const int4*)(src_out) + (t << 2);
        const float4* wp = (const float4*)(w_out) + (t << 2);
        int4   s4[4]; float4 w4[4];
        #pragma unroll
        for (int q = 0; q < 4; ++q) { s4[q] = sp[q]; w4[q] = wp[q]; }
        int   si[16]; float wi[16];
        #pragma unroll
        for (int q = 0; q < 4; ++q) {
            si[4*q+0] = s4[q].x; si[4*q+1] = s4[q].y;
            si[4*q+2] = s4[q].z; si[4*q+3] = s4[q].w;
            wi[4*q+0] = w4[q].x; wi[4*q+1] = w4[q].y;
            wi[4*q+2] = w4[q].z; wi[4*q+3] = w4[q].w;
        }

        float acc[TB];
        #pragma unroll
        for (int j = 0; j < TB; ++j) acc[j] = 0.0f;

        gather16(rd, si, wi, acc);

        // Coalesced 4 KB stores per j across the block.
        #pragma unroll
        for (int j = 0; j < TB; ++j)
            out[(size_t)(b0 + j) * W_NODES + t] = acc[j];
    }
}

extern "C" void kernel_launch(void* const* d_in, const int* in_sizes, int n_in,
                              void* d_out, int out_size, void* d_ws, size_t ws_size,
                              hipStream_t stream) {
    const float* x  = (const float*)d_in[0];
    const int*   sh = (const int*)  d_in[1];
    const float* wh = (const float*)d_in[2];
    const int*   so = (const int*)  d_in[3];
    const float* wo = (const float*)d_in[4];
    float* out = (float*)d_out;

    const int shmem = 2 * BUF_H * (int)sizeof(_Float16);   // 32768 B
    hipFuncSetAttribute(reinterpret_cast<const void*>(genome_net),
                        hipFuncAttributeMaxDynamicSharedMemorySize, shmem);

    genome_net<<<dim3(4096 / TB), dim3(1024), shmem, stream>>>(
        x, sh, wh, so, wo, out);
}